// Round 12
// baseline (204.778 us; speedup 1.0000x reference)
//
#include <hip/hip_runtime.h>

#define B_    16
#define D_    256
#define H_    32
#define W_    32
#define SP    1024        // H_*W_
#define N_TOT 16384       // B_*SP
#define K_    8192
#define ZB    (D_*SP)     // floats per batch in z

#define BIAS_  0.03125f
#define DELTA_ 2.5e-4f

typedef __attribute__((ext_vector_type(8))) short bf16x8;
typedef __attribute__((ext_vector_type(4))) short bf16x4;
typedef __attribute__((ext_vector_type(4))) float f32x4;

#define GLOAD_LDS16(g, l) \
    __builtin_amdgcn_global_load_lds((const __attribute__((address_space(1))) void*)(g), \
                                     (__attribute__((address_space(3))) void*)(l), 16, 0, 0)

__device__ __forceinline__ unsigned short f2bf(float f) {
    unsigned u = __float_as_uint(f);
    u += 0x7FFFu + ((u >> 16) & 1u);          // RNE
    return (unsigned short)(u >> 16);
}

// merge two sorted pairs (a1<=a2), (b1<=b2) -> top-2 in (a1,a2). u32 lex keys.
__device__ __forceinline__ void merge2(unsigned &a1, unsigned &a2,
                                       unsigned b1, unsigned b2) {
    unsigned m1  = min(a1, b1);
    unsigned hi  = max(a1, b1);
    unsigned sel = (a1 < b1) ? a2 : b2;
    a2 = min(hi, sel);
    a1 = m1;
}

// ================= fused prep (round-11 proven, byte-identical) =================

__global__ __launch_bounds__(256)
void prep_kernel(const float* __restrict__ emb, const float* __restrict__ z,
                 short* __restrict__ ET3, short* __restrict__ ZT3,
                 float* __restrict__ zpart, float* __restrict__ enorm,
                 float* __restrict__ enormB, float* __restrict__ out_loss) {
    __shared__ float tr[64][67];     // 16.75 KB, padded (e-blocks leave it unused)
    const int bx = blockIdx.x;
    const int t  = threadIdx.x;
    if (bx < 2048) {
        int k = bx * 4 + (t >> 6);
        int l = t & 63;
        float4 v = *(const float4*)(emb + (size_t)k * D_ + l * 4);
        float sum = v.x*v.x + v.y*v.y + v.z*v.z + v.w*v.w;
        for (int m = 1; m < 64; m <<= 1) sum += __shfl_xor(sum, m, 64);
        if (l == 0) { enorm[k] = sum; enormB[k] = sum + BIAS_; }
        int dcb  = l >> 4;
        int c    = (l >> 1) & 7;
        int half = l & 1;
        bf16x4 o;
        o[0] = (short)f2bf(v.x); o[1] = (short)f2bf(v.y);
        o[2] = (short)f2bf(v.z); o[3] = (short)f2bf(v.w);
        *(bf16x4*)(ET3 + ((size_t)dcb * K_ + k) * 64 + ((c ^ (k & 7)) * 8) + half * 4) = o;
    } else {
        int bz   = bx - 2048;                // 0..1023
        if (bz == 0 && t == 0) *out_loss = 0.f;
        int dcb  = bz & 3;
        int tile = bz >> 2;                  // 0..255, 64 rows each
        int n0   = tile * 64;
        int b    = n0 >> 10;
        int s0   = n0 & 1023;
#pragma unroll
        for (int i = 0; i < 4; ++i) {
            int p = t + i * 256;
            int d = p >> 4;
            int q = p & 15;
            float4 v = *(const float4*)(z + (size_t)b * ZB
                                          + (size_t)(dcb * 64 + d) * SP + s0 + q * 4);
            tr[d][q*4+0] = v.x; tr[d][q*4+1] = v.y;
            tr[d][q*4+2] = v.z; tr[d][q*4+3] = v.w;
        }
        __syncthreads();
        int nl = t >> 2;
        int c2 = t & 3;
        int n  = n0 + nl;
        int sw = n & 7;
        short* dst = ZT3 + ((size_t)dcb * N_TOT + n) * 64;
        float vv[16];
#pragma unroll
        for (int dd = 0; dd < 16; ++dd)
            vv[dd] = tr[c2 * 16 + dd][nl];
        float sum = 0.f;
#pragma unroll
        for (int dd = 0; dd < 16; ++dd) {
            float v = vv[dd];
            sum += v * v;
        }
        zpart[(size_t)(dcb * 4 + c2) * N_TOT + n] = sum;
        bf16x8 o0, o1;
#pragma unroll
        for (int j = 0; j < 8; ++j) { o0[j] = (short)f2bf(vv[j]);
                                      o1[j] = (short)f2bf(vv[8 + j]); }
        *(bf16x8*)(dst + (((c2 * 2)     ^ sw) * 8)) = o0;
        *(bf16x8*)(dst + (((c2 * 2 + 1) ^ sw) * 8)) = o1;
    }
}

// ============== MFMA GEMM + packed-key top-2 (rounds 5-11 proven, byte-identical) ==============

__global__ __launch_bounds__(256, 4)
void mfma_argmin2(const short* __restrict__ ET3, const short* __restrict__ ZT3,
                  const float* __restrict__ enormB, uint2* __restrict__ pv) {
    __shared__ char smem[32768];
    const int t    = threadIdx.x;
    const int wid  = t >> 6, lane = t & 63;
    const int quad = lane >> 4, l16 = lane & 15;
    const int wm   = wid >> 1, wn = wid & 1;
    const int stripe = blockIdx.x >> 7;
    const int n0     = (blockIdx.x & 127) * 128;
    const int swz    = (l16 & 7);

    unsigned r1[4], r2[4];
#pragma unroll
    for (int fj = 0; fj < 4; ++fj) { r1[fj] = 0xFFFFFFFFu; r2[fj] = 0xFFFFFFFFu; }

#pragma unroll 1
    for (int cc = 0; cc < 8; ++cc) {
        const int c0 = stripe * 1024 + cc * 128;
        f32x4 acc[4][4];
#pragma unroll
        for (int fi = 0; fi < 4; ++fi)
#pragma unroll
            for (int fj = 0; fj < 4; ++fj) acc[fi][fj] = (f32x4){0.f, 0.f, 0.f, 0.f};

#pragma unroll 1
        for (int dcb = 0; dcb < 4; ++dcb) {
            __syncthreads();
            const char* gA = (const char*)ET3 + ((size_t)dcb * K_    + c0) * 128;
            const char* gB = (const char*)ZT3 + ((size_t)dcb * N_TOT + n0) * 128;
#pragma unroll
            for (int j = 0; j < 4; ++j) {
                int off = j * 4096 + t * 16;
                GLOAD_LDS16(gA + off, smem + off);
                GLOAD_LDS16(gB + off, smem + 16384 + off);
            }
            __syncthreads();
#pragma unroll
            for (int dc2 = 0; dc2 < 2; ++dc2) {
                bf16x8 af[4], bfv[4];
                const int chm = ((dc2 * 4 + quad) ^ swz) * 16;
#pragma unroll
                for (int fi = 0; fi < 4; ++fi)
                    af[fi] = *(const bf16x8*)(smem + (wm*64 + fi*16 + l16)*128 + chm);
#pragma unroll
                for (int fj = 0; fj < 4; ++fj)
                    bfv[fj] = *(const bf16x8*)(smem + 16384 + (wn*64 + fj*16 + l16)*128 + chm);
#pragma unroll
                for (int fi = 0; fi < 4; ++fi)
#pragma unroll
                    for (int fj = 0; fj < 4; ++fj)
                        acc[fi][fj] = __builtin_amdgcn_mfma_f32_16x16x32_bf16(
                            af[fi], bfv[fj], acc[fi][fj], 0, 0, 0);
            }
        }

        float ekv[4][4];
#pragma unroll
        for (int fi = 0; fi < 4; ++fi) {
            float4 e4 = *(const float4*)(enormB + c0 + wm*64 + fi*16 + quad*4);
            ekv[fi][0]=e4.x; ekv[fi][1]=e4.y; ekv[fi][2]=e4.z; ekv[fi][3]=e4.w;
        }
#pragma unroll
        for (int fj = 0; fj < 4; ++fj) {
#pragma unroll
            for (int fi = 0; fi < 4; ++fi) {
                const unsigned cb = (unsigned)(c0 + wm*64 + fi*16 + quad*4);
                float s0 = fmaf(-2.f, acc[fi][fj].x, ekv[fi][0]);
                float s1 = fmaf(-2.f, acc[fi][fj].y, ekv[fi][1]);
                float s2 = fmaf(-2.f, acc[fi][fj].z, ekv[fi][2]);
                float s3 = fmaf(-2.f, acc[fi][fj].w, ekv[fi][3]);
                unsigned k0 = (__float_as_uint(s0) & 0xFFFFE000u) | (cb + 0u);
                unsigned k1 = (__float_as_uint(s1) & 0xFFFFE000u) | (cb + 1u);
                unsigned k2 = (__float_as_uint(s2) & 0xFFFFE000u) | (cb + 2u);
                unsigned k3 = (__float_as_uint(s3) & 0xFFFFE000u) | (cb + 3u);
                unsigned lo1 = min(k0, k1), hi1 = max(k0, k1);
                unsigned lo2 = min(k2, k3), hi2 = max(k2, k3);
                merge2(lo1, hi1, lo2, hi2);
                merge2(r1[fj], r2[fj], lo1, hi1);
            }
        }
    }

#pragma unroll
    for (int fj = 0; fj < 4; ++fj) {
        unsigned a1 = r1[fj], a2 = r2[fj];
#pragma unroll
        for (int m = 16; m <= 32; m <<= 1) {
            unsigned b1 = __shfl_xor(a1, m, 64);
            unsigned b2 = __shfl_xor(a2, m, 64);
            merge2(a1, a2, b1, b2);
        }
        if (quad == 0) {
            int n = n0 + wn*64 + fj*16 + l16;
            pv[(size_t)(stripe * 2 + wm) * N_TOT + n] = make_uint2(a1, a2);
        }
    }
}

// ============== fused tail v2: 16 rows/block, parallel classify ==============
// Decisions bitwise-identical to rounds 9-11: same min/th/cnt expressions,
// same zn 16-term ordered sum, same exact fp32 dot chain, same output rounding.

__global__ __launch_bounds__(256)
void tail_fused(const uint2* __restrict__ pv, const float* __restrict__ zpart,
                const float* __restrict__ enorm, const float* __restrict__ z,
                const float* __restrict__ emb, float* __restrict__ out,
                float* __restrict__ out_idx, float* __restrict__ loss) {
    __shared__ float eL[16][257];     // 16.4 KB
    __shared__ float zrow[4][256];
    __shared__ int   fid[16];
    __shared__ int   wlL[16];
    __shared__ int   nflag;
    __shared__ float red[4];

    const int t  = threadIdx.x;
    const int n0 = blockIdx.x * 16;
    const int b  = n0 >> 10;
    const int s0 = n0 & 1023;

    if (t == 0) nflag = 0;
    __syncthreads();

    // ---- phase 1: classify 16 rows, 16 lanes per row (one pv-group each) ----
    {
        int r   = t >> 4;                // row 0..15
        int sub = t & 15;                // group 0..15
        int n   = n0 + r;
        uint2 p = pv[(size_t)sub * N_TOT + n];
        unsigned mn = p.x;               // p.x <= p.y
#pragma unroll
        for (int m = 1; m < 16; m <<= 1) mn = min(mn, __shfl_xor(mn, m, 64));
        float smin  = __uint_as_float(mn & 0xFFFFE000u);
        unsigned th = __float_as_uint(smin + DELTA_) | 8191u;
        int cnt = ((p.x <= th) ? 1 : 0) + ((p.y <= th) ? 1 : 0);
#pragma unroll
        for (int m = 1; m < 16; m <<= 1) cnt += __shfl_xor(cnt, m, 64);
        if (sub == 0) {
            if (cnt > 1) {
                int slot = atomicAdd(&nflag, 1);
                wlL[slot] = r;
            } else {
                int c = (int)(mn & 8191u);
                fid[r] = c;
                out_idx[n] = (float)c;
            }
        }
    }
    __syncthreads();

    // ---- phase 2: block-local recheck, one wave per flagged row ----
    const int lane = t & 63;
    const int wid  = t >> 6;
    const int nf   = nflag;
    for (int i = wid; i < nf; i += 4) {
        int r = wlL[i];
        int n = n0 + r;
        unsigned key = 0xFFFFFFFFu;
        if (lane < 32) {
            uint2 p = pv[(size_t)(lane >> 1) * N_TOT + n];
            key = (lane & 1) ? p.y : p.x;
        }
        unsigned mn = key;
#pragma unroll
        for (int m = 1; m < 64; m <<= 1) mn = min(mn, __shfl_xor(mn, m, 64));
        float smin  = __uint_as_float(mn & 0xFFFFE000u);
        unsigned th = __float_as_uint(smin + DELTA_) | 8191u;

        // zn: bit-identical sequential 16-term sum over zpart (znorm's tree)
        float zp = 0.f;
        if (lane < 16) zp = zpart[(size_t)lane * N_TOT + n];
        float zn = 0.f;
#pragma unroll
        for (int dc = 0; dc < 16; ++dc) zn += __shfl(zp, dc, 64);

        const float* zr = z + (size_t)b * ZB + (s0 + r);
#pragma unroll
        for (int j = 0; j < 4; ++j)
            zrow[wid][lane + j * 64] = zr[(size_t)(lane + j * 64) * SP];

        unsigned lexlo = 0xFFFFFFFFu, lexhi = 0xFFFFFFFFu;
        if (key <= th) {
            int c = (int)(key & 8191u);
            const float* er = emb + (size_t)c * D_;
            float dot = 0.f;
#pragma unroll 8
            for (int d = 0; d < D_; ++d)
                dot = fmaf(zrow[wid][d], er[d], dot);
            float s = (zn + enorm[c]) - 2.f * dot;
            unsigned sb = __float_as_uint(s);
            lexhi = sb >> 19;
            lexlo = (sb << 13) | (unsigned)c;
        }
#pragma unroll
        for (int m = 1; m < 64; m <<= 1) {
            unsigned olo = __shfl_xor(lexlo, m, 64);
            unsigned ohi = __shfl_xor(lexhi, m, 64);
            if (ohi < lexhi || (ohi == lexhi && olo < lexlo)) { lexhi = ohi; lexlo = olo; }
        }
        if (lane == 0) {
            int c = (int)(lexlo & 8191u);
            fid[r] = c;
            out_idx[n] = (float)c;
        }
    }
    __syncthreads();

    // ---- phase 3: stage the 16 selected emb rows into LDS ----
#pragma unroll
    for (int i = 0; i < 4; ++i) {
        int p = t + i * 256;             // 1024 float4 slots: row = p>>6, q = p&63
        int row = p >> 6, q = p & 63;
        float4 v = *(const float4*)(emb + (size_t)fid[row] * D_ + q * 4);
        eL[row][q*4+0] = v.x; eL[row][q*4+1] = v.y;
        eL[row][q*4+2] = v.z; eL[row][q*4+3] = v.w;
    }
    __syncthreads();

    // ---- phase 4: stream out + loss (float4 over spatial, 16-wide span) ----
    const int sq = t & 3, dg = t >> 2;   // 4 float4-spans x 64 d-groups
    float lsum = 0.f;
#pragma unroll
    for (int i = 0; i < 4; ++i) {
        int d = dg * 4 + i;
        size_t off = ((size_t)(b * D_ + d)) * SP + s0 + sq * 4;
        float4 z4 = *(const float4*)(z + off);
        float q0 = eL[sq*4+0][d], q1 = eL[sq*4+1][d];
        float q2 = eL[sq*4+2][d], q3 = eL[sq*4+3][d];
        float d0 = q0 - z4.x, d1 = q1 - z4.y;     // fl(q - z)
        float d2 = q2 - z4.z, d3 = q3 - z4.w;
        float4 o4 = make_float4(z4.x + d0, z4.y + d1,   // fl(z + fl(q-z))
                                z4.z + d2, z4.w + d3);
        *(float4*)(out + off) = o4;
        lsum += d0*d0; lsum += d1*d1; lsum += d2*d2; lsum += d3*d3;
    }
    for (int m = 1; m < 64; m <<= 1) lsum += __shfl_xor(lsum, m, 64);
    if ((t & 63) == 0) red[t >> 6] = lsum;
    __syncthreads();
    if (t == 0) {
        float tot = (red[0] + red[1] + red[2] + red[3])
                    * (1.25f / (float)(B_ * SP * D_));
        atomicAdd(loss, tot);
    }
}

// ======================= launch =======================
// ws layout (floats) — NEED = 15,794,176 B (< proven grant):
//   enorm [0,8192)  enormB [8192,16384)  zpart [16384,278528)
//   pv16 [278528,802816)
//   ET3 (short) [802816,1851392)   ZT3 (short) [1851392,3948544)

extern "C" void kernel_launch(void* const* d_in, const int* in_sizes, int n_in,
                              void* d_out, int out_size, void* d_ws, size_t ws_size,
                              hipStream_t stream) {
    const float* z   = (const float*)d_in[0];
    const float* emb = (const float*)d_in[1];
    float* out = (float*)d_out;
    float* w   = (float*)d_ws;

    float* enorm  = w;
    float* enormB = w + 8192;
    float* zpart  = w + 16384;
    uint2* pv     = (uint2*)(w + 278528);
    short* ET3    = (short*)(w + 802816);
    short* ZT3    = (short*)(w + 1851392);

    float* out0     = out;
    float* out_loss = out + (size_t)B_ * D_ * SP;
    float* out_idx  = out_loss + 1;

    prep_kernel<<<3072, 256, 0, stream>>>(emb, z, ET3, ZT3, zpart,
                                          enorm, enormB, out_loss);
    mfma_argmin2<<<1024, 256, 0, stream>>>(ET3, ZT3, enormB, pv);
    tail_fused<<<1024, 256, 0, stream>>>(pv, zpart, enorm, z, emb,
                                         out0, out_idx, out_loss);
}

// Round 14
// 200.091 us; speedup vs baseline: 1.0234x; 1.0234x over previous
//
#include <hip/hip_runtime.h>

#define B_    16
#define D_    256
#define H_    32
#define W_    32
#define SP    1024        // H_*W_
#define N_TOT 16384       // B_*SP
#define K_    8192
#define ZB    (D_*SP)     // floats per batch in z

#define BIAS_  0.03125f
#define DELTA_ 2.5e-4f

typedef __attribute__((ext_vector_type(8))) short bf16x8;
typedef __attribute__((ext_vector_type(4))) short bf16x4;
typedef __attribute__((ext_vector_type(4))) float f32x4;

#define GLOAD_LDS16(g, l) \
    __builtin_amdgcn_global_load_lds((const __attribute__((address_space(1))) void*)(g), \
                                     (__attribute__((address_space(3))) void*)(l), 16, 0, 0)

__device__ __forceinline__ unsigned short f2bf(float f) {
    unsigned u = __float_as_uint(f);
    u += 0x7FFFu + ((u >> 16) & 1u);          // RNE
    return (unsigned short)(u >> 16);
}

// merge two sorted pairs (a1<=a2), (b1<=b2) -> top-2 in (a1,a2). u32 lex keys.
__device__ __forceinline__ void merge2(unsigned &a1, unsigned &a2,
                                       unsigned b1, unsigned b2) {
    unsigned m1  = min(a1, b1);
    unsigned hi  = max(a1, b1);
    unsigned sel = (a1 < b1) ? a2 : b2;
    a2 = min(hi, sel);
    a1 = m1;
}

// ================= fused prep (rounds 11-12 proven, byte-identical) =================

__global__ __launch_bounds__(256)
void prep_kernel(const float* __restrict__ emb, const float* __restrict__ z,
                 short* __restrict__ ET3, short* __restrict__ ZT3,
                 float* __restrict__ zpart, float* __restrict__ enorm,
                 float* __restrict__ enormB, float* __restrict__ out_loss) {
    __shared__ float tr[64][67];     // 16.75 KB, padded (e-blocks leave it unused)
    const int bx = blockIdx.x;
    const int t  = threadIdx.x;
    if (bx < 2048) {
        int k = bx * 4 + (t >> 6);
        int l = t & 63;
        float4 v = *(const float4*)(emb + (size_t)k * D_ + l * 4);
        float sum = v.x*v.x + v.y*v.y + v.z*v.z + v.w*v.w;
        for (int m = 1; m < 64; m <<= 1) sum += __shfl_xor(sum, m, 64);
        if (l == 0) { enorm[k] = sum; enormB[k] = sum + BIAS_; }
        int dcb  = l >> 4;
        int c    = (l >> 1) & 7;
        int half = l & 1;
        bf16x4 o;
        o[0] = (short)f2bf(v.x); o[1] = (short)f2bf(v.y);
        o[2] = (short)f2bf(v.z); o[3] = (short)f2bf(v.w);
        *(bf16x4*)(ET3 + ((size_t)dcb * K_ + k) * 64 + ((c ^ (k & 7)) * 8) + half * 4) = o;
    } else {
        int bz   = bx - 2048;                // 0..1023
        if (bz == 0 && t == 0) *out_loss = 0.f;
        int dcb  = bz & 3;
        int tile = bz >> 2;                  // 0..255, 64 rows each
        int n0   = tile * 64;
        int b    = n0 >> 10;
        int s0   = n0 & 1023;
#pragma unroll
        for (int i = 0; i < 4; ++i) {
            int p = t + i * 256;
            int d = p >> 4;
            int q = p & 15;
            float4 v = *(const float4*)(z + (size_t)b * ZB
                                          + (size_t)(dcb * 64 + d) * SP + s0 + q * 4);
            tr[d][q*4+0] = v.x; tr[d][q*4+1] = v.y;
            tr[d][q*4+2] = v.z; tr[d][q*4+3] = v.w;
        }
        __syncthreads();
        int nl = t >> 2;
        int c2 = t & 3;
        int n  = n0 + nl;
        int sw = n & 7;
        short* dst = ZT3 + ((size_t)dcb * N_TOT + n) * 64;
        float vv[16];
#pragma unroll
        for (int dd = 0; dd < 16; ++dd)
            vv[dd] = tr[c2 * 16 + dd][nl];
        float sum = 0.f;
#pragma unroll
        for (int dd = 0; dd < 16; ++dd) {
            float v = vv[dd];
            sum += v * v;
        }
        zpart[(size_t)(dcb * 4 + c2) * N_TOT + n] = sum;
        bf16x8 o0, o1;
#pragma unroll
        for (int j = 0; j < 8; ++j) { o0[j] = (short)f2bf(vv[j]);
                                      o1[j] = (short)f2bf(vv[8 + j]); }
        *(bf16x8*)(dst + (((c2 * 2)     ^ sw) * 8)) = o0;
        *(bf16x8*)(dst + (((c2 * 2 + 1) ^ sw) * 8)) = o1;
    }
}

// ============== MFMA GEMM + packed-key top-2 (rounds 5-12 proven, byte-identical) ==============

__global__ __launch_bounds__(256, 4)
void mfma_argmin2(const short* __restrict__ ET3, const short* __restrict__ ZT3,
                  const float* __restrict__ enormB, uint2* __restrict__ pv) {
    __shared__ char smem[32768];
    const int t    = threadIdx.x;
    const int wid  = t >> 6, lane = t & 63;
    const int quad = lane >> 4, l16 = lane & 15;
    const int wm   = wid >> 1, wn = wid & 1;
    const int stripe = blockIdx.x >> 7;
    const int n0     = (blockIdx.x & 127) * 128;
    const int swz    = (l16 & 7);

    unsigned r1[4], r2[4];
#pragma unroll
    for (int fj = 0; fj < 4; ++fj) { r1[fj] = 0xFFFFFFFFu; r2[fj] = 0xFFFFFFFFu; }

#pragma unroll 1
    for (int cc = 0; cc < 8; ++cc) {
        const int c0 = stripe * 1024 + cc * 128;
        f32x4 acc[4][4];
#pragma unroll
        for (int fi = 0; fi < 4; ++fi)
#pragma unroll
            for (int fj = 0; fj < 4; ++fj) acc[fi][fj] = (f32x4){0.f, 0.f, 0.f, 0.f};

#pragma unroll 1
        for (int dcb = 0; dcb < 4; ++dcb) {
            __syncthreads();
            const char* gA = (const char*)ET3 + ((size_t)dcb * K_    + c0) * 128;
            const char* gB = (const char*)ZT3 + ((size_t)dcb * N_TOT + n0) * 128;
#pragma unroll
            for (int j = 0; j < 4; ++j) {
                int off = j * 4096 + t * 16;
                GLOAD_LDS16(gA + off, smem + off);
                GLOAD_LDS16(gB + off, smem + 16384 + off);
            }
            __syncthreads();
#pragma unroll
            for (int dc2 = 0; dc2 < 2; ++dc2) {
                bf16x8 af[4], bfv[4];
                const int chm = ((dc2 * 4 + quad) ^ swz) * 16;
#pragma unroll
                for (int fi = 0; fi < 4; ++fi)
                    af[fi] = *(const bf16x8*)(smem + (wm*64 + fi*16 + l16)*128 + chm);
#pragma unroll
                for (int fj = 0; fj < 4; ++fj)
                    bfv[fj] = *(const bf16x8*)(smem + 16384 + (wn*64 + fj*16 + l16)*128 + chm);
#pragma unroll
                for (int fi = 0; fi < 4; ++fi)
#pragma unroll
                    for (int fj = 0; fj < 4; ++fj)
                        acc[fi][fj] = __builtin_amdgcn_mfma_f32_16x16x32_bf16(
                            af[fi], bfv[fj], acc[fi][fj], 0, 0, 0);
            }
        }

        float ekv[4][4];
#pragma unroll
        for (int fi = 0; fi < 4; ++fi) {
            float4 e4 = *(const float4*)(enormB + c0 + wm*64 + fi*16 + quad*4);
            ekv[fi][0]=e4.x; ekv[fi][1]=e4.y; ekv[fi][2]=e4.z; ekv[fi][3]=e4.w;
        }
#pragma unroll
        for (int fj = 0; fj < 4; ++fj) {
#pragma unroll
            for (int fi = 0; fi < 4; ++fi) {
                const unsigned cb = (unsigned)(c0 + wm*64 + fi*16 + quad*4);
                float s0 = fmaf(-2.f, acc[fi][fj].x, ekv[fi][0]);
                float s1 = fmaf(-2.f, acc[fi][fj].y, ekv[fi][1]);
                float s2 = fmaf(-2.f, acc[fi][fj].z, ekv[fi][2]);
                float s3 = fmaf(-2.f, acc[fi][fj].w, ekv[fi][3]);
                unsigned k0 = (__float_as_uint(s0) & 0xFFFFE000u) | (cb + 0u);
                unsigned k1 = (__float_as_uint(s1) & 0xFFFFE000u) | (cb + 1u);
                unsigned k2 = (__float_as_uint(s2) & 0xFFFFE000u) | (cb + 2u);
                unsigned k3 = (__float_as_uint(s3) & 0xFFFFE000u) | (cb + 3u);
                unsigned lo1 = min(k0, k1), hi1 = max(k0, k1);
                unsigned lo2 = min(k2, k3), hi2 = max(k2, k3);
                merge2(lo1, hi1, lo2, hi2);
                merge2(r1[fj], r2[fj], lo1, hi1);
            }
        }
    }

#pragma unroll
    for (int fj = 0; fj < 4; ++fj) {
        unsigned a1 = r1[fj], a2 = r2[fj];
#pragma unroll
        for (int m = 16; m <= 32; m <<= 1) {
            unsigned b1 = __shfl_xor(a1, m, 64);
            unsigned b2 = __shfl_xor(a2, m, 64);
            merge2(a1, a2, b1, b2);
        }
        if (quad == 0) {
            int n = n0 + wn*64 + fj*16 + l16;
            pv[(size_t)(stripe * 2 + wm) * N_TOT + n] = make_uint2(a1, a2);
        }
    }
}

// ============== fused tail (round-12 proven, byte-identical) ==============

__global__ __launch_bounds__(256)
void tail_fused(const uint2* __restrict__ pv, const float* __restrict__ zpart,
                const float* __restrict__ enorm, const float* __restrict__ z,
                const float* __restrict__ emb, float* __restrict__ out,
                float* __restrict__ out_idx, float* __restrict__ loss) {
    __shared__ float eL[16][257];     // 16.4 KB
    __shared__ float zrow[4][256];
    __shared__ int   fid[16];
    __shared__ int   wlL[16];
    __shared__ int   nflag;
    __shared__ float red[4];

    const int t  = threadIdx.x;
    const int n0 = blockIdx.x * 16;
    const int b  = n0 >> 10;
    const int s0 = n0 & 1023;

    if (t == 0) nflag = 0;
    __syncthreads();

    // ---- phase 1: classify 16 rows, 16 lanes per row (one pv-group each) ----
    {
        int r   = t >> 4;                // row 0..15
        int sub = t & 15;                // group 0..15
        int n   = n0 + r;
        uint2 p = pv[(size_t)sub * N_TOT + n];
        unsigned mn = p.x;               // p.x <= p.y
#pragma unroll
        for (int m = 1; m < 16; m <<= 1) mn = min(mn, __shfl_xor(mn, m, 64));
        float smin  = __uint_as_float(mn & 0xFFFFE000u);
        unsigned th = __float_as_uint(smin + DELTA_) | 8191u;
        int cnt = ((p.x <= th) ? 1 : 0) + ((p.y <= th) ? 1 : 0);
#pragma unroll
        for (int m = 1; m < 16; m <<= 1) cnt += __shfl_xor(cnt, m, 64);
        if (sub == 0) {
            if (cnt > 1) {
                int slot = atomicAdd(&nflag, 1);
                wlL[slot] = r;
            } else {
                int c = (int)(mn & 8191u);
                fid[r] = c;
                out_idx[n] = (float)c;
            }
        }
    }
    __syncthreads();

    // ---- phase 2: block-local recheck, one wave per flagged row ----
    const int lane = t & 63;
    const int wid  = t >> 6;
    const int nf   = nflag;
    for (int i = wid; i < nf; i += 4) {
        int r = wlL[i];
        int n = n0 + r;
        unsigned key = 0xFFFFFFFFu;
        if (lane < 32) {
            uint2 p = pv[(size_t)(lane >> 1) * N_TOT + n];
            key = (lane & 1) ? p.y : p.x;
        }
        unsigned mn = key;
#pragma unroll
        for (int m = 1; m < 64; m <<= 1) mn = min(mn, __shfl_xor(mn, m, 64));
        float smin  = __uint_as_float(mn & 0xFFFFE000u);
        unsigned th = __float_as_uint(smin + DELTA_) | 8191u;

        // zn: bit-identical sequential 16-term sum over zpart (znorm's tree)
        float zp = 0.f;
        if (lane < 16) zp = zpart[(size_t)lane * N_TOT + n];
        float zn = 0.f;
#pragma unroll
        for (int dc = 0; dc < 16; ++dc) zn += __shfl(zp, dc, 64);

        const float* zr = z + (size_t)b * ZB + (s0 + r);
#pragma unroll
        for (int j = 0; j < 4; ++j)
            zrow[wid][lane + j * 64] = zr[(size_t)(lane + j * 64) * SP];

        unsigned lexlo = 0xFFFFFFFFu, lexhi = 0xFFFFFFFFu;
        if (key <= th) {
            int c = (int)(key & 8191u);
            const float* er = emb + (size_t)c * D_;
            float dot = 0.f;
#pragma unroll 8
            for (int d = 0; d < D_; ++d)
                dot = fmaf(zrow[wid][d], er[d], dot);
            float s = (zn + enorm[c]) - 2.f * dot;
            unsigned sb = __float_as_uint(s);
            lexhi = sb >> 19;
            lexlo = (sb << 13) | (unsigned)c;
        }
#pragma unroll
        for (int m = 1; m < 64; m <<= 1) {
            unsigned olo = __shfl_xor(lexlo, m, 64);
            unsigned ohi = __shfl_xor(lexhi, m, 64);
            if (ohi < lexhi || (ohi == lexhi && olo < lexlo)) { lexhi = ohi; lexlo = olo; }
        }
        if (lane == 0) {
            int c = (int)(lexlo & 8191u);
            fid[r] = c;
            out_idx[n] = (float)c;
        }
    }
    __syncthreads();

    // ---- phase 3: stage the 16 selected emb rows into LDS ----
#pragma unroll
    for (int i = 0; i < 4; ++i) {
        int p = t + i * 256;             // 1024 float4 slots: row = p>>6, q = p&63
        int row = p >> 6, q = p & 63;
        float4 v = *(const float4*)(emb + (size_t)fid[row] * D_ + q * 4);
        eL[row][q*4+0] = v.x; eL[row][q*4+1] = v.y;
        eL[row][q*4+2] = v.z; eL[row][q*4+3] = v.w;
    }
    __syncthreads();

    // ---- phase 4: stream out + loss (float4 over spatial, 16-wide span) ----
    const int sq = t & 3, dg = t >> 2;   // 4 float4-spans x 64 d-groups
    float lsum = 0.f;
#pragma unroll
    for (int i = 0; i < 4; ++i) {
        int d = dg * 4 + i;
        size_t off = ((size_t)(b * D_ + d)) * SP + s0 + sq * 4;
        float4 z4 = *(const float4*)(z + off);
        float q0 = eL[sq*4+0][d], q1 = eL[sq*4+1][d];
        float q2 = eL[sq*4+2][d], q3 = eL[sq*4+3][d];
        float d0 = q0 - z4.x, d1 = q1 - z4.y;     // fl(q - z)
        float d2 = q2 - z4.z, d3 = q3 - z4.w;
        float4 o4 = make_float4(z4.x + d0, z4.y + d1,   // fl(z + fl(q-z))
                                z4.z + d2, z4.w + d3);
        *(float4*)(out + off) = o4;
        lsum += d0*d0; lsum += d1*d1; lsum += d2*d2; lsum += d3*d3;
    }
    for (int m = 1; m < 64; m <<= 1) lsum += __shfl_xor(lsum, m, 64);
    if ((t & 63) == 0) red[t >> 6] = lsum;
    __syncthreads();
    if (t == 0) {
        float tot = (red[0] + red[1] + red[2] + red[3])
                    * (1.25f / (float)(B_ * SP * D_));
        atomicAdd(loss, tot);
    }
}

// ======================= launch =======================
// ws layout (floats) — NEED = 15,794,176 B (proven grant):
//   enorm [0,8192)  enormB [8192,16384)  zpart [16384,278528)
//   pv16 [278528,802816)
//   ET3 (short) [802816,1851392)   ZT3 (short) [1851392,3948544)

extern "C" void kernel_launch(void* const* d_in, const int* in_sizes, int n_in,
                              void* d_out, int out_size, void* d_ws, size_t ws_size,
                              hipStream_t stream) {
    const float* z   = (const float*)d_in[0];
    const float* emb = (const float*)d_in[1];
    float* out = (float*)d_out;
    float* w   = (float*)d_ws;

    float* enorm  = w;
    float* enormB = w + 8192;
    float* zpart  = w + 16384;
    uint2* pv     = (uint2*)(w + 278528);
    short* ET3    = (short*)(w + 802816);
    short* ZT3    = (short*)(w + 1851392);

    float* out0     = out;
    float* out_loss = out + (size_t)B_ * D_ * SP;
    float* out_idx  = out_loss + 1;

    prep_kernel<<<3072, 256, 0, stream>>>(emb, z, ET3, ZT3, zpart,
                                          enorm, enormB, out_loss);
    mfma_argmin2<<<1024, 256, 0, stream>>>(ET3, ZT3, enormB, pv);
    tail_fused<<<1024, 256, 0, stream>>>(pv, zpart, enorm, z, emb,
                                         out0, out_idx, out_loss);
}